// Round 18
// baseline (606.384 us; speedup 1.0000x reference)
//
#include <hip/hip_runtime.h>

#define TT 2048
#define BB 512
#define HH 64
#define HIST 64
#define HPAD 80   // slice ks at word ks*20 -> bank-quads {0-3},{20-23},{8-11},{28-31}: conflict-free

typedef float f32x2 __attribute__((ext_vector_type(2)));
typedef float f32x4 __attribute__((ext_vector_type(4)));

#define FMA2(a, b, c) __builtin_elementwise_fma((a), (b), (c))
#define LO2(q) __builtin_shufflevector((q), (q), 0, 1)
#define HI2(q) __builtin_shufflevector((q), (q), 2, 3)

// quad DPP add: v += value from lane^1 (0xB1) / lane^2 (0x4E); full quad sum
#define DPP_ADD(v, ctrl) \
    ((v) + __int_as_float(__builtin_amdgcn_update_dpp(0, __float_as_int(v), (ctrl), 0xF, 0xF, false)))

// One wave per block, TWO columns per wave, K-split-4 per column (R16 math,
// HW-validated). Col B's ~115-cyc compute fills col A's LDS write->read
// turnaround and vice versa. 256 blocks = 1 wave/CU: DS pipe uncontended.
__global__ __launch_bounds__(64, 1) void rnn_fused(
    const float* __restrict__ x,     // [T][B]
    const float* __restrict__ h0,    // [B][H]
    const float* __restrict__ Wih,   // [H]
    const float* __restrict__ Whh,   // [H][H]
    const float* __restrict__ bih,   // [H]
    const float* __restrict__ bhh,   // [H]
    const float* __restrict__ Wlin,  // [H]
    const float* __restrict__ blin,  // [1]
    float* __restrict__ y,           // [T][B]
    float* __restrict__ hN)          // [B][H]
{
    __shared__ float xsh[2][TT + 4];                     // x columns (+pad)
    __shared__ __align__(16) float hist[2][HIST][HPAD];  // h rings, padded layout
    __shared__ __align__(16) float wlin_sh[HPAD];        // wlin in padded layout

    const int b0   = 2 * blockIdx.x;
    const int b1   = b0 + 1;
    const int lane = threadIdx.x;   // 0..63
    const int hl   = lane >> 2;     // 0..15
    const int ks   = lane & 3;      // K-slice 0..3
    const int d    = ks * 16 + hl;  // this lane's output index
    const int slot = ks * 20 + hl;  // padded word for h[d]

    // ---- Prologue (single wave, in-order DS pipe: no barriers) ----
    // zero hist gaps (word 16-19 of each 20-word slice stay 0 forever)
    float* hflat = &hist[0][0][0];
    for (int i = lane; i < 2 * HIST * HPAD; i += 64) hflat[i] = 0.f;
    for (int i = lane; i < HPAD; i += 64) wlin_sh[i] = 0.f;

    for (int i = lane; i < TT; i += 64) {
        xsh[0][i] = x[(size_t)i * BB + b0];
        xsh[1][i] = x[(size_t)i * BB + b1];
    }
    if (lane < 4) { xsh[0][TT + lane] = 0.f; xsh[1][TT + lane] = 0.f; }

    const float KSC = 2.885390081777927f;  // 2/ln2 pre-scale (tanh via exp2)

    // weights (shared by both columns): group g output = g*16+hl, my K-slice
    // wr[g*8+i] = {W[g*16+hl][ks*16+2i], W[g*16+hl][ks*16+2i+1]} * KSC
    f32x2 wr[32];
#pragma unroll
    for (int g = 0; g < 4; ++g) {
        const float4* rowp = reinterpret_cast<const float4*>(Whh + (g * 16 + hl) * HH + ks * 16);
        const float4 v0 = rowp[0], v1 = rowp[1], v2 = rowp[2], v3 = rowp[3];
        wr[g * 8 + 0] = f32x2{v0.x * KSC, v0.y * KSC};
        wr[g * 8 + 1] = f32x2{v0.z * KSC, v0.w * KSC};
        wr[g * 8 + 2] = f32x2{v1.x * KSC, v1.y * KSC};
        wr[g * 8 + 3] = f32x2{v1.z * KSC, v1.w * KSC};
        wr[g * 8 + 4] = f32x2{v2.x * KSC, v2.y * KSC};
        wr[g * 8 + 5] = f32x2{v2.z * KSC, v2.w * KSC};
        wr[g * 8 + 6] = f32x2{v3.x * KSC, v3.y * KSC};
        wr[g * 8 + 7] = f32x2{v3.z * KSC, v3.w * KSC};
    }
    const float wihs  = Wih[d] * KSC;
    const float biass = (bih[d] + bhh[d]) * KSC;
    const float bl    = blin[0];

    wlin_sh[slot] = Wlin[d];

    // seed h_0 at ring slot HIST-1 (both columns), then prime the reads
    hist[0][HIST - 1][slot] = h0[(size_t)b0 * HH + d];
    hist[1][HIST - 1][slot] = h0[(size_t)b1 * HH + d];

    const f32x4* pr0 = reinterpret_cast<const f32x4*>(&hist[0][HIST - 1][ks * 20]);
    const f32x4* pr1 = reinterpret_cast<const f32x4*>(&hist[1][HIST - 1][ks * 20]);
    f32x4 A0 = pr0[0], A1 = pr0[1], A2 = pr0[2], A3 = pr0[3];
    f32x4 B0 = pr1[0], B1 = pr1[1], B2 = pr1[2], B3 = pr1[3];

    float xw0 = fmaf(xsh[0][0], wihs, biass);
    float xw1 = fmaf(xsh[1][0], wihs, biass);
    float hv0 = 0.f, hv1 = 0.f;

// per-column step: compute from 4 regs, tanh, publish, re-read, xw prefetch
#define COL_STEP(C, R0, R1, R2, R3, HV, XW)                                        \
    {                                                                              \
        const f32x2 e0 = LO2(R0), e1 = HI2(R0), e2 = LO2(R1), e3 = HI2(R1);        \
        const f32x2 e4 = LO2(R2), e5 = HI2(R2), e6 = LO2(R3), e7 = HI2(R3);        \
        f32x2 g0a = {0.f, 0.f}, g0b = {0.f, 0.f};                                  \
        f32x2 g1a = {0.f, 0.f}, g1b = {0.f, 0.f};                                  \
        f32x2 g2a = {0.f, 0.f}, g2b = {0.f, 0.f};                                  \
        f32x2 g3a = {0.f, 0.f}, g3b = {0.f, 0.f};                                  \
        g0a = FMA2(e0, wr[0],  g0a); g0b = FMA2(e1, wr[1],  g0b);                  \
        g0a = FMA2(e2, wr[2],  g0a); g0b = FMA2(e3, wr[3],  g0b);                  \
        g0a = FMA2(e4, wr[4],  g0a); g0b = FMA2(e5, wr[5],  g0b);                  \
        g0a = FMA2(e6, wr[6],  g0a); g0b = FMA2(e7, wr[7],  g0b);                  \
        g1a = FMA2(e0, wr[8],  g1a); g1b = FMA2(e1, wr[9],  g1b);                  \
        g1a = FMA2(e2, wr[10], g1a); g1b = FMA2(e3, wr[11], g1b);                  \
        g1a = FMA2(e4, wr[12], g1a); g1b = FMA2(e5, wr[13], g1b);                  \
        g1a = FMA2(e6, wr[14], g1a); g1b = FMA2(e7, wr[15], g1b);                  \
        g2a = FMA2(e0, wr[16], g2a); g2b = FMA2(e1, wr[17], g2b);                  \
        g2a = FMA2(e2, wr[18], g2a); g2b = FMA2(e3, wr[19], g2b);                  \
        g2a = FMA2(e4, wr[20], g2a); g2b = FMA2(e5, wr[21], g2b);                  \
        g2a = FMA2(e6, wr[22], g2a); g2b = FMA2(e7, wr[23], g2b);                  \
        g3a = FMA2(e0, wr[24], g3a); g3b = FMA2(e1, wr[25], g3b);                  \
        g3a = FMA2(e2, wr[26], g3a); g3b = FMA2(e3, wr[27], g3b);                  \
        g3a = FMA2(e4, wr[28], g3a); g3b = FMA2(e5, wr[29], g3b);                  \
        g3a = FMA2(e6, wr[30], g3a); g3b = FMA2(e7, wr[31], g3b);                  \
        const f32x2 h0v = g0a + g0b, h1v = g1a + g1b;                              \
        const f32x2 h2v = g2a + g2b, h3v = g3a + g3b;                              \
        float s0 = h0v[0] + h0v[1];                                                \
        float s1 = h1v[0] + h1v[1];                                                \
        float s2 = h2v[0] + h2v[1];                                                \
        float s3 = h3v[0] + h3v[1];                                                \
        s0 = DPP_ADD(s0, 0xB1); s0 = DPP_ADD(s0, 0x4E);                            \
        s1 = DPP_ADD(s1, 0xB1); s1 = DPP_ADD(s1, 0x4E);                            \
        s2 = DPP_ADD(s2, 0xB1); s2 = DPP_ADD(s2, 0x4E);                            \
        s3 = DPP_ADD(s3, 0xB1); s3 = DPP_ADD(s3, 0x4E);                            \
        const float sA = (ks & 1) ? s1 : s0;                                       \
        const float sB = (ks & 1) ? s3 : s2;                                       \
        const float s  = (ks & 2) ? sB : sA;                                       \
        const float acc = s + (XW);                                                \
        const float ex = __builtin_amdgcn_exp2f(acc);                              \
        const float rc = __builtin_amdgcn_rcpf(ex + 1.0f);                         \
        (HV) = fmaf(-2.0f, rc, 1.0f);                                              \
        hist[C][ti][slot] = (HV);                                                  \
        const f32x4* rp_ = reinterpret_cast<const f32x4*>(&hist[C][ti][ks * 20]);  \
        R0 = rp_[0]; R1 = rp_[1]; R2 = rp_[2]; R3 = rp_[3];                        \
        (XW) = fmaf(xsh[C][t + 1], wihs, biass);                                   \
    }

    // ---- Recurrence ----
#pragma unroll 1
    for (int tc = 0; tc < TT; tc += HIST) {
#pragma unroll 2
        for (int ti = 0; ti < HIST; ++ti) {
            const int t = tc + ti;
            COL_STEP(0, A0, A1, A2, A3, hv0, xw0)
            COL_STEP(1, B0, B1, B2, B3, hv1, xw1)
        }

        // ---- bulk y: lane -> t = tc + lane; gaps are zero x zero ----
        {
            const f32x4* wl = reinterpret_cast<const f32x4*>(&wlin_sh[0]);
            const f32x4* r0 = reinterpret_cast<const f32x4*>(&hist[0][lane][0]);
            const f32x4* r1 = reinterpret_cast<const f32x4*>(&hist[1][lane][0]);
            f32x2 a0 = {0.f, 0.f}, a1 = {0.f, 0.f};
#pragma unroll
            for (int i = 0; i < HPAD / 4; ++i) {
                const f32x4 qw = wl[i];
                const f32x4 q0 = r0[i];
                const f32x4 q1 = r1[i];
                a0 = FMA2(LO2(q0), LO2(qw), a0);
                a0 = FMA2(HI2(q0), HI2(qw), a0);
                a1 = FMA2(LO2(q1), LO2(qw), a1);
                a1 = FMA2(HI2(q1), HI2(qw), a1);
            }
            y[(size_t)(tc + lane) * BB + b0] = a0[0] + a0[1] + bl;
            y[(size_t)(tc + lane) * BB + b1] = a1[0] + a1[1] + bl;
        }
        // same wave: next chunk's ring writes are ordered after these reads
    }

    // ---- Epilogue ----
    hN[(size_t)b0 * HH + d] = hv0;
    hN[(size_t)b1 * HH + d] = hv1;
}

extern "C" void kernel_launch(void* const* d_in, const int* in_sizes, int n_in,
                              void* d_out, int out_size, void* d_ws, size_t ws_size,
                              hipStream_t stream) {
    const float* x    = (const float*)d_in[0];
    const float* h0   = (const float*)d_in[1];
    const float* Wih  = (const float*)d_in[2];
    const float* Whh  = (const float*)d_in[3];
    const float* bih  = (const float*)d_in[4];
    const float* bhh  = (const float*)d_in[5];
    const float* Wlin = (const float*)d_in[6];
    const float* blin = (const float*)d_in[7];

    float* y  = (float*)d_out;            // [T*B]
    float* hN = (float*)d_out + TT * BB;  // [B*H]

    rnn_fused<<<dim3(BB / 2), dim3(64), 0, stream>>>(x, h0, Wih, Whh, bih, bhh, Wlin, blin, y, hN);
}

// Round 19
// 427.684 us; speedup vs baseline: 1.4178x; 1.4178x over previous
//
#include <hip/hip_runtime.h>

#define TT 2048
#define BB 512
#define HH 64
#define HIST 64
#define HISTP 65   // odd padded stride -> conflict-free row & column access

typedef float f32x2 __attribute__((ext_vector_type(2)));
typedef float f32x4 __attribute__((ext_vector_type(4)));
typedef unsigned uint2v __attribute__((ext_vector_type(2)));

#define FMA2(a, b, c) __builtin_elementwise_fma((a), (b), (c))
#define LO2(q) __builtin_shufflevector((q), (q), 0, 1)
#define HI2(q) __builtin_shufflevector((q), (q), 2, 3)

// DPP mov: value of v from lane (lane ^ mask) — XOR patterns only.
// All ctrl codes HW-validated by rounds 15/17 (passing runs).
#define DPPM(v, ctrl) \
    __int_as_float(__builtin_amdgcn_update_dpp(0, __float_as_int(v), (ctrl), 0xF, 0xF, false))

// POLARITY-INDEPENDENT partner fetch across lane^16 / lane^32 (validated R15/R17):
// r = permlane_swap(v,v) returns {even-dup, odd-dup} in some order; sum is
// order-independent; partner = sum - own.
__device__ __forceinline__ float recv16(float v) {
#if __has_builtin(__builtin_amdgcn_permlane16_swap)
    uint2v r = __builtin_amdgcn_permlane16_swap(__float_as_uint(v), __float_as_uint(v), false, false);
    return (__uint_as_float(r[0]) + __uint_as_float(r[1])) - v;
#else
    float a = v, b = v;
    asm volatile("s_nop 1\n\tv_permlane16_swap_b32 %0, %1" : "+v"(a), "+v"(b));
    return (a + b) - v;
#endif
}
__device__ __forceinline__ float recv32(float v) {
#if __has_builtin(__builtin_amdgcn_permlane32_swap)
    uint2v r = __builtin_amdgcn_permlane32_swap(__float_as_uint(v), __float_as_uint(v), false, false);
    return (__uint_as_float(r[0]) + __uint_as_float(r[1])) - v;
#else
    float a = v, b = v;
    asm volatile("s_nop 1\n\tv_permlane32_swap_b32 %0, %1" : "+v"(a), "+v"(b));
    return (a + b) - v;
#endif
}

// One wave per block (512 blocks = 2 waves/CU on separate SIMDs). Recurrence is
// 100% register/cross-lane (R17 structure, validated): lane L owns h_L; 15
// XOR-DPP movs gather the row's 16 values; 32 pk_fma (targets paired into the
// pk lanes, weights pre-paired, r splatted via op_sel) form partials for 4
// outputs; 2-stage permlane reduce-scatter lands output d at lane d.
__global__ __launch_bounds__(64, 1) void rnn_fused(
    const float* __restrict__ x,     // [T][B]
    const float* __restrict__ h0,    // [B][H]
    const float* __restrict__ Wih,   // [H]
    const float* __restrict__ Whh,   // [H][H]
    const float* __restrict__ bih,   // [H]
    const float* __restrict__ bhh,   // [H]
    const float* __restrict__ Wlin,  // [H]
    const float* __restrict__ blin,  // [1]
    float* __restrict__ y,           // [T][B]
    float* __restrict__ hN)          // [B][H]
{
    __shared__ float wsh[HH * HH];        // W_hh staging for the setup gather
    __shared__ float xsh[TT + 4];         // x column (+pad for t+1 probe)
    __shared__ float hist[HH][HISTP];     // wlin-premultiplied h, transposed

    const int b    = blockIdx.x;    // batch column
    const int lane = threadIdx.x;   // 0..63 == hidden index owned by this lane
    const int rb   = lane & 15;     // in-row index
    const int R    = lane >> 4;     // DPP row == K-slice index

    // ---- Prologue (single wave, in-order DS pipe: no barriers) ----
    for (int i = lane; i < HH * HH; i += 64) wsh[i] = Whh[i];
    for (int i = lane; i < TT; i += 64)      xsh[i] = x[(size_t)i * BB + b];
    if (lane < 4) xsh[TT + lane] = 0.f;

    const float KSC = 2.885390081777927f;  // 2/ln2 pre-scale (tanh via exp2)

    // pk-paired weights: rotation r[m] = h_{16R + (rb^m)} multiplies
    //   wp01[m] = {W[rb][k(m)],    W[16+rb][k(m)]} * KSC
    //   wp23[m] = {W[32+rb][k(m)], W[48+rb][k(m)]} * KSC,  k(m)=16R+(rb^m)
    f32x2 wp01[16], wp23[16];
#pragma unroll
    for (int m = 0; m < 16; ++m) {
        const int k = 16 * R + (rb ^ m);
        wp01[m] = f32x2{wsh[(rb)      * HH + k] * KSC, wsh[(16 + rb) * HH + k] * KSC};
        wp23[m] = f32x2{wsh[(32 + rb) * HH + k] * KSC, wsh[(48 + rb) * HH + k] * KSC};
    }

    const float wihs  = Wih[lane] * KSC;
    const float biass = (bih[lane] + bhh[lane]) * KSC;
    const float wlinL = Wlin[lane];
    const float bl    = blin[0];

    const bool L4 = (lane & 16) != 0;
    const bool L5 = (lane & 32) != 0;

    float hval = h0[(size_t)b * HH + lane];   // h_lane lives in lane forever
    float xw   = fmaf(xsh[0], wihs, biass);   // x-projection for step 0

    // ---- Recurrence ----
#pragma unroll 1
    for (int tc = 0; tc < TT; tc += HIST) {
#pragma unroll 2
        for (int ti = 0; ti < HIST; ++ti) {
            const int t = tc + ti;

            // 15-mov XOR-DPP tree: r[m] = h value of lane^m (row-local)
            float r[16];
            r[0]  = hval;
            r[1]  = DPPM(hval,  0xB1);   // xor1
            r[2]  = DPPM(hval,  0x4E);   // xor2
            r[3]  = DPPM(r[2],  0xB1);   // xor3
            r[7]  = DPPM(hval,  0x141);  // xor7 (row_half_mirror)
            r[6]  = DPPM(r[7],  0xB1);
            r[5]  = DPPM(r[7],  0x4E);
            r[4]  = DPPM(r[5],  0xB1);
            r[15] = DPPM(hval,  0x140);  // xor15 (row_mirror)
            r[14] = DPPM(r[15], 0xB1);
            r[13] = DPPM(r[15], 0x4E);
            r[12] = DPPM(r[13], 0xB1);
            r[8]  = DPPM(r[15], 0x141);  // xor8
            r[9]  = DPPM(r[8],  0xB1);
            r[10] = DPPM(r[8],  0x4E);
            r[11] = DPPM(r[10], 0xB1);

            // 32 pk_fma in 4 chains of 8: pk element = target, r splatted
            f32x2 aA = {0.f, 0.f}, aB = {0.f, 0.f};  // targets {rb, 16+rb}
            f32x2 cA = {0.f, 0.f}, cB = {0.f, 0.f};  // targets {32+rb, 48+rb}
#pragma unroll
            for (int m = 0; m < 16; m += 2) {
                const f32x2 rm0 = {r[m], r[m]};
                const f32x2 rm1 = {r[m + 1], r[m + 1]};
                aA = FMA2(rm0, wp01[m],     aA);
                cA = FMA2(rm0, wp23[m],     cA);
                aB = FMA2(rm1, wp01[m + 1], aB);
                cB = FMA2(rm1, wp23[m + 1], cB);
            }
            const f32x2 a01 = aA + aB;   // {p0, p1}
            const f32x2 a23 = cA + cB;   // {p2, p3}
            const float p0 = a01[0], p1 = a01[1];
            const float p2 = a23[0], p3 = a23[1];

            // stage 1 (lane^16): keep a0==L4 partials, fetch partner's same
            const float keep0 = L4 ? p1 : p0;
            const float send0 = L4 ? p0 : p1;
            const float keep1 = L4 ? p3 : p2;
            const float send1 = L4 ? p2 : p3;
            const float q0 = keep0 + recv16(send0);
            const float q1 = keep1 + recv16(send1);

            // stage 2 (lane^32): keep a1==L5
            const float keep = L5 ? q1 : q0;
            const float send = L5 ? q0 : q1;
            const float acc  = keep + recv32(send) + xw;  // lands at lane d==L

            // tanh = 1 - 2/(2^{acc}+1)   (pre-scaled by 2/ln2)
            const float e2 = __builtin_amdgcn_exp2f(acc);
            const float rr = __builtin_amdgcn_rcpf(e2 + 1.0f);
            hval = fmaf(-2.0f, rr, 1.0f);

            // y ring: premultiplied by wlin; stride 65 -> 2 lanes/bank (free)
            hist[lane][ti] = hval * wlinL;

            // next-step x projection (uniform broadcast read, off-chain)
            xw = fmaf(xsh[t + 1], wihs, biass);
        }

        // ---- bulk y: lane -> t = tc + lane; column sum, conflict-free ----
        {
            float acc = bl;
#pragma unroll
            for (int d2 = 0; d2 < HH; ++d2)
                acc += hist[d2][lane];
            y[(size_t)(tc + lane) * BB + b] = acc;
        }
        // same wave: next chunk's ring writes are ordered after these reads
    }

    // ---- Epilogue ----
    hN[(size_t)b * HH + lane] = hval;
}

extern "C" void kernel_launch(void* const* d_in, const int* in_sizes, int n_in,
                              void* d_out, int out_size, void* d_ws, size_t ws_size,
                              hipStream_t stream) {
    const float* x    = (const float*)d_in[0];
    const float* h0   = (const float*)d_in[1];
    const float* Wih  = (const float*)d_in[2];
    const float* Whh  = (const float*)d_in[3];
    const float* bih  = (const float*)d_in[4];
    const float* bhh  = (const float*)d_in[5];
    const float* Wlin = (const float*)d_in[6];
    const float* blin = (const float*)d_in[7];

    float* y  = (float*)d_out;            // [T*B]
    float* hN = (float*)d_out + TT * BB;  // [B*H]

    rnn_fused<<<dim3(BB), dim3(64), 0, stream>>>(x, h0, Wih, Whh, bih, bhh, Wlin, blin, y, hN);
}